// Round 12
// baseline (173.791 us; speedup 1.0000x reference)
//
#include <hip/hip_runtime.h>
#include <hip/hip_bf16.h>
#include <hip/hip_fp16.h>

// MQA: B=4 H=16 S=2048 DIM=1024 DPH=64. fp16 MFMA path, fp32 accumulate.
// R12 = R11 + GEMM double-buffered LDS with prefetch-before-compute (T3-min,
// m248v2 +10%) + XCD-aware block swizzle on GEMMs (T1) + setprio around attn
// MFMA clusters (T5, m191 +4-7%). Attention math byte-identical to R11.
// ws layout (bytes):
//   xh    @ 0          16,777,216   [8192][1024] f16
//   wqkvT @ 16777216    2,359,296   [1152][1024] f16
//   woT   @ 19136512    2,097,152   [1024 d][1024 f] f16
//   qh    @ 21233664   16,777,216   [B][H][S][64] f16 (PRE-SCALED by 0.125*log2e)
//   kh    @ 38010880    1,048,576   [B][S][64] f16
//   vth   @ 39059456    1,048,576   [B][64][S] f16 (V transposed)
//   oh    @ 40108032   16,777,216   [B][S][1024] f16

typedef _Float16 f16x8 __attribute__((ext_vector_type(8)));
typedef _Float16 f16x4 __attribute__((ext_vector_type(4)));
typedef _Float16 f16x2 __attribute__((ext_vector_type(2)));
typedef float f32x4 __attribute__((ext_vector_type(4)));
typedef float f32x16 __attribute__((ext_vector_type(16)));

#define MFMA16(a, b, c) __builtin_amdgcn_mfma_f32_16x16x32_f16((a), (b), (c), 0, 0, 0)
#define MFMA32(a, b, c) __builtin_amdgcn_mfma_f32_32x32x16_f16((a), (b), (c), 0, 0, 0)
#define PKRTZ(a, b) __builtin_bit_cast(f16x2, __builtin_amdgcn_cvt_pkrtz((a), (b)))

__device__ __forceinline__ void gll16(const void* g, void* l) {
  __builtin_amdgcn_global_load_lds(
      (__attribute__((address_space(1))) void*)const_cast<void*>(g),
      (__attribute__((address_space(3))) void*)l, 16, 0, 0);
}

// fused input packing: blocks [0,4096) pack x (8 f32->f16 per thread);
// blocks [4096,12800) pack weights (1 elem per thread)
__global__ __launch_bounds__(256) void pack_all_kernel(
    const float* __restrict__ x, const float* __restrict__ Wq,
    const float* __restrict__ Wk, const float* __restrict__ Wv,
    const float* __restrict__ Wo,
    _Float16* __restrict__ xh, _Float16* __restrict__ wqkvT,
    _Float16* __restrict__ woT) {
  int bid = blockIdx.x;
  if (bid < 4096) {
    int i = bid * 256 + threadIdx.x;
    const float4* s = (const float4*)x + (size_t)i * 2;
    float4 a = s[0], b = s[1];
    f16x8 h;
    h[0] = (_Float16)a.x; h[1] = (_Float16)a.y; h[2] = (_Float16)a.z; h[3] = (_Float16)a.w;
    h[4] = (_Float16)b.x; h[5] = (_Float16)b.y; h[6] = (_Float16)b.z; h[7] = (_Float16)b.w;
    ((f16x8*)xh)[i] = h;
    return;
  }
  int i = (bid - 4096) * 256 + threadIdx.x;
  if (i < 1048576) {
    int n = i >> 10, d = i & 1023;
    int h = n >> 6, e = n & 63;
    wqkvT[i] = (_Float16)Wq[h * 65536 + d * 64 + e];
  } else if (i < 1114112) {
    int j = i - 1048576;
    int e = j >> 10, d = j & 1023;
    wqkvT[i] = (_Float16)Wk[d * 64 + e];
  } else if (i < 1179648) {
    int j = i - 1114112;
    int e = j >> 10, d = j & 1023;
    wqkvT[i] = (_Float16)Wv[d * 64 + e];
  } else {
    int j = i - 1179648;
    int d = j >> 10, f = j & 1023;
    woT[j] = (_Float16)Wo[f * 1024 + d];
  }
}

// -------- m97-structure GEMM + double-buffered LDS prefetch (R12) --------
struct GemmAcc {
  f32x4 acc[4][4];
};

// abuf/bbuf are [2][128*32] f16 (dbuf). One barrier per K-step; STAGE(k+1)
// issued before compute(k) so global_load_lds latency hides under MFMA.
__device__ __forceinline__ void gemm128_core(
    const _Float16* __restrict__ A, const _Float16* __restrict__ Bp,
    int m0, int n0, _Float16* abuf, _Float16* bbuf, GemmAcc& g) {
  const int tid = threadIdx.x;
  const int lane = tid & 63, wave = tid >> 6;
  const int wr = wave >> 1, wc = wave & 1;
  const int g4 = lane >> 4, l15 = lane & 15;

  const char* Ag = (const char*)(A + (size_t)m0 * 1024);
  const char* Bg = (const char*)(Bp + (size_t)n0 * 1024);

  const int c0 = tid, c1 = tid + 256;
  const size_t aoff0 = (size_t)(c0 >> 2) * 2048 + (size_t)(c0 & 3) * 16;
  const size_t aoff1 = (size_t)(c1 >> 2) * 2048 + (size_t)(c1 & 3) * 16;

  auto STAGE = [&](int kstep, int buf) {
    const size_t kb = (size_t)kstep * 64;  // 32 f16 = 64B per K-step
    char* la = (char*)abuf + buf * 8192;
    char* lb = (char*)bbuf + buf * 8192;
    gll16(Ag + aoff0 + kb, la + c0 * 16);
    gll16(Ag + aoff1 + kb, la + c1 * 16);
    gll16(Bg + aoff0 + kb, lb + c0 * 16);
    gll16(Bg + aoff1 + kb, lb + c1 * 16);
  };

  const int arow = ((wr << 6) + l15) * 64 + (g4 << 4);
  const int brow = ((wc << 6) + l15) * 64 + (g4 << 4);

  STAGE(0, 0);
  __syncthreads();

  for (int k = 0; k < 32; k++) {
    const int cur = k & 1;
    if (k + 1 < 32) STAGE(k + 1, cur ^ 1);
    const char* la = (const char*)abuf + cur * 8192;
    const char* lb = (const char*)bbuf + cur * 8192;
    f16x8 af[4], bf[4];
    #pragma unroll
    for (int mt = 0; mt < 4; mt++) af[mt] = *(const f16x8*)(la + arow + mt * 1024);
    #pragma unroll
    for (int nt = 0; nt < 4; nt++) bf[nt] = *(const f16x8*)(lb + brow + nt * 1024);
    #pragma unroll
    for (int mt = 0; mt < 4; mt++)
      #pragma unroll
      for (int nt = 0; nt < 4; nt++)
        g.acc[mt][nt] = MFMA16(af[mt], bf[nt], g.acc[mt][nt]);
    __syncthreads();
  }
}

__global__ __launch_bounds__(256) void gemm_qkv_kernel(
    const _Float16* __restrict__ xh, const _Float16* __restrict__ wT,
    const float* __restrict__ bq, const float* __restrict__ bk,
    const float* __restrict__ bv,
    _Float16* __restrict__ qh, _Float16* __restrict__ kh,
    _Float16* __restrict__ vth) {
  __shared__ __align__(16) _Float16 abuf[2][128 * 32];
  __shared__ __align__(16) _Float16 bbuf[2][128 * 32];
  const int lane = threadIdx.x & 63, wave = threadIdx.x >> 6;
  const int wr = wave >> 1, wc = wave & 1;
  const int g4 = lane >> 4, l15 = lane & 15;
  // XCD-aware swizzle over linearized grid (576 blocks, 576%8==0)
  const int nwg = gridDim.x * gridDim.y;
  const int orig = blockIdx.y * gridDim.x + blockIdx.x;
  const int cpx = nwg >> 3;
  const int swzb = (orig & 7) * cpx + (orig >> 3);
  const int m0 = (swzb % gridDim.x) * 128;
  const int n0 = (swzb / gridDim.x) * 128;
  GemmAcc g = {};
  gemm128_core(xh, wT, m0, n0, abuf[0], bbuf[0], g);

  const float QSCALE = 0.18033688011112042f;  // 0.125 * log2(e)
  #pragma unroll
  for (int mt = 0; mt < 4; mt++) {
    int rbase = m0 + wr * 64 + mt * 16 + (g4 << 2);
    int bb = rbase >> 11;
    int s = rbase & 2047;
    #pragma unroll
    for (int nt = 0; nt < 4; nt++) {
      int n = n0 + wc * 64 + nt * 16 + l15;
      if (n < 1024) {
        float bias = bq[n];
        int h = n >> 6, e = n & 63;
        _Float16* dst = qh + (((size_t)(bb * 16 + h) * 2048 + s) * 64 + e);
        #pragma unroll
        for (int r = 0; r < 4; r++)
          dst[(size_t)r * 64] = (_Float16)((g.acc[mt][nt][r] + bias) * QSCALE);
      } else if (n < 1088) {
        int e = n - 1024;
        float bias = bk[e];
        _Float16* dst = kh + ((size_t)bb * 2048 + s) * 64 + e;
        #pragma unroll
        for (int r = 0; r < 4; r++) dst[(size_t)r * 64] = (_Float16)(g.acc[mt][nt][r] + bias);
      } else {
        int e = n - 1088;
        float bias = bv[e];
        f16x4 t;
        #pragma unroll
        for (int r = 0; r < 4; r++) t[r] = (_Float16)(g.acc[mt][nt][r] + bias);
        *(f16x4*)(vth + ((size_t)bb * 64 + e) * 2048 + s) = t;
      }
    }
  }
}

__global__ __launch_bounds__(256) void gemm_out_kernel(
    const _Float16* __restrict__ oh, const _Float16* __restrict__ woT,
    const float* __restrict__ bo, float* __restrict__ out) {
  __shared__ __align__(16) _Float16 abuf[2][128 * 32];
  __shared__ __align__(16) _Float16 bbuf[2][128 * 32];
  const int lane = threadIdx.x & 63, wave = threadIdx.x >> 6;
  const int wr = wave >> 1, wc = wave & 1;
  const int g4 = lane >> 4, l15 = lane & 15;
  // XCD-aware swizzle (512 blocks, 512%8==0)
  const int nwg = gridDim.x * gridDim.y;
  const int orig = blockIdx.y * gridDim.x + blockIdx.x;
  const int cpx = nwg >> 3;
  const int swzb = (orig & 7) * cpx + (orig >> 3);
  const int m0 = (swzb % gridDim.x) * 128;
  const int n0 = (swzb / gridDim.x) * 128;
  GemmAcc g = {};
  gemm128_core(oh, woT, m0, n0, abuf[0], bbuf[0], g);

  #pragma unroll
  for (int mt = 0; mt < 4; mt++) {
    int rbase = m0 + wr * 64 + mt * 16 + (g4 << 2);
    #pragma unroll
    for (int nt = 0; nt < 4; nt++) {
      int n = n0 + wc * 64 + nt * 16 + l15;
      float bias = bo[n];
      #pragma unroll
      for (int r = 0; r < 4; r++)
        out[(size_t)(rbase + r) * 1024 + n] = g.acc[mt][nt][r] + bias;
    }
  }
}

// ---------------- Flash attention, swapped-operand 32x32x16 (R12) ----------------
// Identical math to R11; + setprio(1) around MFMA clusters (T5).
__global__ __launch_bounds__(1024) void attn_kernel(
    const _Float16* __restrict__ qh, const _Float16* __restrict__ kh,
    const _Float16* __restrict__ vth, _Float16* __restrict__ oh) {
  __shared__ __align__(16) _Float16 smem[32768];  // 64KB
  const int tid = threadIdx.x;
  const int lane = tid & 63, wave = tid >> 6;
  const int l31 = lane & 31, h = lane >> 5;
  const int b = blockIdx.z, hd = blockIdx.y;
  const int q0 = blockIdx.x * 512;

  const _Float16* Qrow = qh + (((size_t)(b * 16 + hd) * 2048 + q0 + wave * 32 + l31) * 64);
  f16x8 qf[4];
  #pragma unroll
  for (int s = 0; s < 4; s++) qf[s] = *(const f16x8*)(Qrow + s * 16 + h * 8);

  const char* Kb = (const char*)(kh + (size_t)b * 2048 * 64);
  const char* Vb = (const char*)(vth + (size_t)b * 64 * 2048);

  // staging: waves 0-7 stage K (chunks 0-511), waves 8-15 stage V (chunks 0-511)
  const bool isK = tid < 512;
  const char* src;
  int dstbase;
  {
    int c = isK ? tid : (tid - 512);
    int m = c >> 3, c8 = c & 7;
    int gc = c8 ^ (m & 7);
    if (isK) {
      int tsrc = (m & 51) | ((m & 4) << 1) | ((m & 8) >> 1);  // swap bits 2,3
      src = Kb + (size_t)tsrc * 128 + gc * 16;
      dstbase = c * 16;             // K region base 0
    } else {
      src = Vb + (size_t)m * 4096 + gc * 16;
      dstbase = 16384 + c * 16;     // V region base 16KB
    }
  }
  char* const ldsb = (char*)smem;  // K: +buf*8192 ; V: +16384+buf*8192
  const size_t srcstep = isK ? 8192 : 128;  // per-tile source advance (bytes)

  const int swz = l31 & 7;
  int ro[4][2];
  #pragma unroll
  for (int s = 0; s < 4; s++) {
    int ch = ((2 * s + h) ^ swz) << 4;
    ro[s][0] = l31 * 128 + ch;
    ro[s][1] = (l31 + 32) * 128 + ch;
  }

  float negm = 0.f, l_run = 0.f;   // negm = -m_run
  f32x16 oa0 = {}, oa1 = {};
  const f16x2 one2 = {(_Float16)1.0f, (_Float16)1.0f};

  auto STAGE = [&](int t, int buf) {
    gll16(src + (size_t)t * srcstep, ldsb + buf * 8192 + dstbase);
  };

  // prologue: tile 0 into buffer 0
  STAGE(0, 0);
  __syncthreads();

  for (int it = 0; it < 32; ++it) {
    const int cur = it & 1;
    const char* kb = ldsb + cur * 8192;
    const char* vb = kb + 16384;

    // prefetch next tile into other buffer (in flight during compute)
    if (it + 1 < 32) STAGE(it + 1, cur ^ 1);

    // ---- S^T = K . Q^T ; C-init = -m_run (free max-subtraction) ----
    f32x16 s0, s1;
    #pragma unroll
    for (int i = 0; i < 16; i++) { s0[i] = negm; s1[i] = negm; }
    __builtin_amdgcn_s_setprio(1);
    #pragma unroll
    for (int s = 0; s < 4; s++) {
      f16x8 a0 = *(const f16x8*)(kb + ro[s][0]);
      f16x8 a1 = *(const f16x8*)(kb + ro[s][1]);
      s0 = MFMA32(a0, qf[s], s0);
      s1 = MFMA32(a1, qf[s], s1);
    }
    __builtin_amdgcn_s_setprio(0);

    // ---- shifted row max (lane owns q-row l31; partner lane^32) ----
    float vm[8];
    #pragma unroll
    for (int i = 0; i < 8; i++)
      vm[i] = fmaxf(fmaxf(s0[i], s0[i + 8]), fmaxf(s1[i], s1[i + 8]));
    float pm = fmaxf(fmaxf(fmaxf(vm[0], vm[1]), fmaxf(vm[2], vm[3])),
                     fmaxf(fmaxf(vm[4], vm[5]), fmaxf(vm[6], vm[7])));
    pm = fmaxf(pm, __shfl_xor(pm, 32));

    if (__any(pm > 8.0f)) {  // defer-max trigger (rare, wave-uniform)
      float delta = fmaxf(pm, 0.f);
      float al = __builtin_amdgcn_exp2f(-delta);
      l_run *= al;
      oa0 *= al;
      oa1 *= al;
      negm -= delta;
      #pragma unroll
      for (int i = 0; i < 16; i++) { s0[i] -= delta; s1[i] -= delta; }
    }

    // ---- P = exp2(S) (already max-shifted; raw v_exp_f32, input <= +8) ----
    #pragma unroll
    for (int i = 0; i < 16; i++) {
      s0[i] = __builtin_amdgcn_exp2f(s0[i]);
      s1[i] = __builtin_amdgcn_exp2f(s1[i]);
    }

    // ---- pack to f16 (RTZ) + fdot2 row sums ----
    f16x2 pp[16];
    #pragma unroll
    for (int j = 0; j < 8; j++) pp[j] = PKRTZ(s0[2 * j], s0[2 * j + 1]);
    #pragma unroll
    for (int j = 0; j < 8; j++) pp[8 + j] = PKRTZ(s1[2 * j], s1[2 * j + 1]);

    float ps0 = 0.f, ps1 = 0.f, ps2 = 0.f, ps3 = 0.f;
    #pragma unroll
    for (int j = 0; j < 4; j++) {
      ps0 = __builtin_amdgcn_fdot2(pp[j], one2, ps0, false);
      ps1 = __builtin_amdgcn_fdot2(pp[4 + j], one2, ps1, false);
      ps2 = __builtin_amdgcn_fdot2(pp[8 + j], one2, ps2, false);
      ps3 = __builtin_amdgcn_fdot2(pp[12 + j], one2, ps3, false);
    }
    l_run += (ps0 + ps1) + (ps2 + ps3);

    // ---- P B-frags: pf[s] = pp[4s..4s+3] ----
    f16x8 pf[4];
    #pragma unroll
    for (int s = 0; s < 4; s++) {
      f16x4 lo = __builtin_shufflevector(pp[s * 4], pp[s * 4 + 1], 0, 1, 2, 3);
      f16x4 hi = __builtin_shufflevector(pp[s * 4 + 2], pp[s * 4 + 3], 0, 1, 2, 3);
      pf[s] = __builtin_shufflevector(lo, hi, 0, 1, 2, 3, 4, 5, 6, 7);
    }

    // ---- O^T += V^T . P^T ----
    __builtin_amdgcn_s_setprio(1);
    #pragma unroll
    for (int s = 0; s < 4; s++) {
      f16x8 v0 = *(const f16x8*)(vb + ro[s][0]);
      f16x8 v1 = *(const f16x8*)(vb + ro[s][1]);
      oa0 = MFMA32(v0, pf[s], oa0);
      oa1 = MFMA32(v1, pf[s], oa1);
    }
    __builtin_amdgcn_s_setprio(0);

    __syncthreads();  // drains vmcnt -> next tile staged; buffer safe to flip
  }

  // ---- epilogue: combine l halves, de-transpose O^T via swizzled LDS ----
  l_run += __shfl_xor(l_run, 32);
  _Float16* ob = smem + wave * 2048;  // [32 q][64 e] per wave; 16 x 4KB = 64KB
  float invl = 1.0f / l_run;
  #pragma unroll
  for (int rh = 0; rh < 4; rh++) {
    f16x4 t0, t1;
    #pragma unroll
    for (int j = 0; j < 4; j++) {
      t0[j] = (_Float16)(oa0[rh * 4 + j] * invl);
      t1[j] = (_Float16)(oa1[rh * 4 + j] * invl);
    }
    *(f16x4*)&ob[l31 * 64 + ((rh ^ swz) * 8) + h * 4] = t0;
    *(f16x4*)&ob[l31 * 64 + (((rh + 4) ^ swz) * 8) + h * 4] = t1;
  }
  const int q_ = lane >> 1, hf = lane & 1;
  const size_t orow = ((size_t)b * 2048 + q0 + wave * 32 + q_) * 1024 + hd * 64 + hf * 32;
  #pragma unroll
  for (int c = 0; c < 4; c++) {
    f16x8 v = *(const f16x8*)&ob[q_ * 64 + (((hf * 4 + c) ^ (q_ & 7)) * 8)];
    *(f16x8*)(oh + orow + c * 8) = v;
  }
}

extern "C" void kernel_launch(void* const* d_in, const int* in_sizes, int n_in,
                              void* d_out, int out_size, void* d_ws, size_t ws_size,
                              hipStream_t stream) {
  const float* x  = (const float*)d_in[0];
  const float* Wq = (const float*)d_in[1];
  const float* bq = (const float*)d_in[2];
  const float* Wk = (const float*)d_in[3];
  const float* bk = (const float*)d_in[4];
  const float* Wv = (const float*)d_in[5];
  const float* bv = (const float*)d_in[6];
  const float* Wo = (const float*)d_in[7];
  const float* bo = (const float*)d_in[8];
  float* out = (float*)d_out;
  char* ws = (char*)d_ws;

  _Float16* xh   = (_Float16*)(ws);
  _Float16* wqkv = (_Float16*)(ws + 16777216);
  _Float16* woT  = (_Float16*)(ws + 19136512);
  _Float16* qh   = (_Float16*)(ws + 21233664);
  _Float16* kh   = (_Float16*)(ws + 38010880);
  _Float16* vth  = (_Float16*)(ws + 39059456);
  _Float16* oh   = (_Float16*)(ws + 40108032);

  pack_all_kernel<<<12800, 256, 0, stream>>>(x, Wq, Wk, Wv, Wo, xh, wqkv, woT);
  gemm_qkv_kernel<<<dim3(64, 9), 256, 0, stream>>>(xh, wqkv, bq, bk, bv, qh, kh, vth);
  attn_kernel<<<dim3(4, 16, 4), 1024, 0, stream>>>(qh, kh, vth, oh);
  gemm_out_kernel<<<dim3(64, 8), 256, 0, stream>>>(oh, woT, bo, out);
}

// Round 13
// 161.214 us; speedup vs baseline: 1.0780x; 1.0780x over previous
//
#include <hip/hip_runtime.h>
#include <hip/hip_bf16.h>
#include <hip/hip_fp16.h>

// MQA: B=4 H=16 S=2048 DIM=1024 DPH=64. fp16 MFMA path, fp32 accumulate.
// R13 = exact revert to R11 (best verified 161.2 us). R12's GEMM dbuf (m99/
// m100-class neutral-to-negative), XCD swizzle (L3-fit regime: -2%), and attn
// setprio (lockstep-null, m190) all isolated as losses by per-dispatch
// counters and removed.
// ws layout (bytes):
//   xh    @ 0          16,777,216   [8192][1024] f16
//   wqkvT @ 16777216    2,359,296   [1152][1024] f16
//   woT   @ 19136512    2,097,152   [1024 d][1024 f] f16
//   qh    @ 21233664   16,777,216   [B][H][S][64] f16 (PRE-SCALED by 0.125*log2e)
//   kh    @ 38010880    1,048,576   [B][S][64] f16
//   vth   @ 39059456    1,048,576   [B][64][S] f16 (V transposed)
//   oh    @ 40108032   16,777,216   [B][S][1024] f16

typedef _Float16 f16x8 __attribute__((ext_vector_type(8)));
typedef _Float16 f16x4 __attribute__((ext_vector_type(4)));
typedef _Float16 f16x2 __attribute__((ext_vector_type(2)));
typedef float f32x4 __attribute__((ext_vector_type(4)));
typedef float f32x16 __attribute__((ext_vector_type(16)));

#define MFMA16(a, b, c) __builtin_amdgcn_mfma_f32_16x16x32_f16((a), (b), (c), 0, 0, 0)
#define MFMA32(a, b, c) __builtin_amdgcn_mfma_f32_32x32x16_f16((a), (b), (c), 0, 0, 0)
#define PKRTZ(a, b) __builtin_bit_cast(f16x2, __builtin_amdgcn_cvt_pkrtz((a), (b)))

__device__ __forceinline__ void gll16(const void* g, void* l) {
  __builtin_amdgcn_global_load_lds(
      (__attribute__((address_space(1))) void*)const_cast<void*>(g),
      (__attribute__((address_space(3))) void*)l, 16, 0, 0);
}

// fused input packing: blocks [0,4096) pack x (8 f32->f16 per thread);
// blocks [4096,12800) pack weights (1 elem per thread)
__global__ __launch_bounds__(256) void pack_all_kernel(
    const float* __restrict__ x, const float* __restrict__ Wq,
    const float* __restrict__ Wk, const float* __restrict__ Wv,
    const float* __restrict__ Wo,
    _Float16* __restrict__ xh, _Float16* __restrict__ wqkvT,
    _Float16* __restrict__ woT) {
  int bid = blockIdx.x;
  if (bid < 4096) {
    int i = bid * 256 + threadIdx.x;
    const float4* s = (const float4*)x + (size_t)i * 2;
    float4 a = s[0], b = s[1];
    f16x8 h;
    h[0] = (_Float16)a.x; h[1] = (_Float16)a.y; h[2] = (_Float16)a.z; h[3] = (_Float16)a.w;
    h[4] = (_Float16)b.x; h[5] = (_Float16)b.y; h[6] = (_Float16)b.z; h[7] = (_Float16)b.w;
    ((f16x8*)xh)[i] = h;
    return;
  }
  int i = (bid - 4096) * 256 + threadIdx.x;
  if (i < 1048576) {
    int n = i >> 10, d = i & 1023;
    int h = n >> 6, e = n & 63;
    wqkvT[i] = (_Float16)Wq[h * 65536 + d * 64 + e];
  } else if (i < 1114112) {
    int j = i - 1048576;
    int e = j >> 10, d = j & 1023;
    wqkvT[i] = (_Float16)Wk[d * 64 + e];
  } else if (i < 1179648) {
    int j = i - 1114112;
    int e = j >> 10, d = j & 1023;
    wqkvT[i] = (_Float16)Wv[d * 64 + e];
  } else {
    int j = i - 1179648;
    int d = j >> 10, f = j & 1023;
    woT[j] = (_Float16)Wo[f * 1024 + d];
  }
}

// ---------------- m97-structure GEMM (R2-proven) ----------------
struct GemmAcc {
  f32x4 acc[4][4];
};

__device__ __forceinline__ void gemm128_core(
    const _Float16* __restrict__ A, const _Float16* __restrict__ Bp,
    int m0, int n0, _Float16* abuf, _Float16* bbuf, GemmAcc& g) {
  const int tid = threadIdx.x;
  const int lane = tid & 63, wave = tid >> 6;
  const int wr = wave >> 1, wc = wave & 1;
  const int g4 = lane >> 4, l15 = lane & 15;

  const char* Ag = (const char*)(A + (size_t)m0 * 1024);
  const char* Bg = (const char*)(Bp + (size_t)n0 * 1024);

  const int c0 = tid, c1 = tid + 256;
  const size_t aoff0 = (size_t)(c0 >> 2) * 2048 + (size_t)(c0 & 3) * 16;
  const size_t aoff1 = (size_t)(c1 >> 2) * 2048 + (size_t)(c1 & 3) * 16;
  char* ldsa0 = (char*)abuf + c0 * 16;
  char* ldsa1 = (char*)abuf + c1 * 16;
  char* ldsb0 = (char*)bbuf + c0 * 16;
  char* ldsb1 = (char*)bbuf + c1 * 16;

  const char* ar[4];
  const char* br[4];
  #pragma unroll
  for (int mt = 0; mt < 4; mt++)
    ar[mt] = (const char*)abuf + ((wr << 6) + (mt << 4) + l15) * 64 + (g4 << 4);
  #pragma unroll
  for (int nt = 0; nt < 4; nt++)
    br[nt] = (const char*)bbuf + ((wc << 6) + (nt << 4) + l15) * 64 + (g4 << 4);

  for (int k0 = 0; k0 < 1024; k0 += 32) {
    const size_t kb = (size_t)k0 * 2;
    gll16(Ag + aoff0 + kb, ldsa0);
    gll16(Ag + aoff1 + kb, ldsa1);
    gll16(Bg + aoff0 + kb, ldsb0);
    gll16(Bg + aoff1 + kb, ldsb1);
    __syncthreads();
    f16x8 af[4], bf[4];
    #pragma unroll
    for (int mt = 0; mt < 4; mt++) af[mt] = *(const f16x8*)ar[mt];
    #pragma unroll
    for (int nt = 0; nt < 4; nt++) bf[nt] = *(const f16x8*)br[nt];
    #pragma unroll
    for (int mt = 0; mt < 4; mt++)
      #pragma unroll
      for (int nt = 0; nt < 4; nt++)
        g.acc[mt][nt] = MFMA16(af[mt], bf[nt], g.acc[mt][nt]);
    __syncthreads();
  }
}

__global__ __launch_bounds__(256) void gemm_qkv_kernel(
    const _Float16* __restrict__ xh, const _Float16* __restrict__ wT,
    const float* __restrict__ bq, const float* __restrict__ bk,
    const float* __restrict__ bv,
    _Float16* __restrict__ qh, _Float16* __restrict__ kh,
    _Float16* __restrict__ vth) {
  __shared__ __align__(16) _Float16 abuf[128 * 32];
  __shared__ __align__(16) _Float16 bbuf[128 * 32];
  const int lane = threadIdx.x & 63, wave = threadIdx.x >> 6;
  const int wr = wave >> 1, wc = wave & 1;
  const int g4 = lane >> 4, l15 = lane & 15;
  const int m0 = blockIdx.x * 128;
  const int n0 = blockIdx.y * 128;
  GemmAcc g = {};
  gemm128_core(xh, wT, m0, n0, abuf, bbuf, g);

  const float QSCALE = 0.18033688011112042f;  // 0.125 * log2(e)
  #pragma unroll
  for (int mt = 0; mt < 4; mt++) {
    int rbase = m0 + wr * 64 + mt * 16 + (g4 << 2);
    int bb = rbase >> 11;
    int s = rbase & 2047;
    #pragma unroll
    for (int nt = 0; nt < 4; nt++) {
      int n = n0 + wc * 64 + nt * 16 + l15;
      if (n < 1024) {
        float bias = bq[n];
        int h = n >> 6, e = n & 63;
        _Float16* dst = qh + (((size_t)(bb * 16 + h) * 2048 + s) * 64 + e);
        #pragma unroll
        for (int r = 0; r < 4; r++)
          dst[(size_t)r * 64] = (_Float16)((g.acc[mt][nt][r] + bias) * QSCALE);
      } else if (n < 1088) {
        int e = n - 1024;
        float bias = bk[e];
        _Float16* dst = kh + ((size_t)bb * 2048 + s) * 64 + e;
        #pragma unroll
        for (int r = 0; r < 4; r++) dst[(size_t)r * 64] = (_Float16)(g.acc[mt][nt][r] + bias);
      } else {
        int e = n - 1088;
        float bias = bv[e];
        f16x4 t;
        #pragma unroll
        for (int r = 0; r < 4; r++) t[r] = (_Float16)(g.acc[mt][nt][r] + bias);
        *(f16x4*)(vth + ((size_t)bb * 64 + e) * 2048 + s) = t;
      }
    }
  }
}

__global__ __launch_bounds__(256) void gemm_out_kernel(
    const _Float16* __restrict__ oh, const _Float16* __restrict__ woT,
    const float* __restrict__ bo, float* __restrict__ out) {
  __shared__ __align__(16) _Float16 abuf[128 * 32];
  __shared__ __align__(16) _Float16 bbuf[128 * 32];
  const int lane = threadIdx.x & 63, wave = threadIdx.x >> 6;
  const int wr = wave >> 1, wc = wave & 1;
  const int g4 = lane >> 4, l15 = lane & 15;
  const int m0 = blockIdx.x * 128;
  const int n0 = blockIdx.y * 128;
  GemmAcc g = {};
  gemm128_core(oh, woT, m0, n0, abuf, bbuf, g);

  #pragma unroll
  for (int mt = 0; mt < 4; mt++) {
    int rbase = m0 + wr * 64 + mt * 16 + (g4 << 2);
    #pragma unroll
    for (int nt = 0; nt < 4; nt++) {
      int n = n0 + wc * 64 + nt * 16 + l15;
      float bias = bo[n];
      #pragma unroll
      for (int r = 0; r < 4; r++)
        out[(size_t)(rbase + r) * 1024 + n] = g.acc[mt][nt][r] + bias;
    }
  }
}

// ---------------- Flash attention, swapped-operand 32x32x16 (R11-proven) ----------------
// Block: 512 q-rows of one (b,hd); 16 waves x 32 q-rows share one K/V tile.
// Grid 256 = 1 block/CU, 16 phase-diverse waves. KV tile = 64, dbl-buffered.
// Staging split: waves 0-7 load K chunks, waves 8-15 load V chunks (1 gll16/thr).
// LDS 64KB: main loop uses first 32KB (K dbuf | V dbuf); epilogue uses all 64KB.
// 16B-chunk XOR swizzle on GLOBAL source (LDS linear). K rows bit-permuted
// (swap t-bits 2<->3) so QK^T C-regs feed PV B-frags directly.
// Softmax: max folded into MFMA C-init; defer-max THR=8 in-branch; raw
// v_exp_f32; pkrtz pack; fdot2 row sums; l-combine deferred to epilogue.
__global__ __launch_bounds__(1024) void attn_kernel(
    const _Float16* __restrict__ qh, const _Float16* __restrict__ kh,
    const _Float16* __restrict__ vth, _Float16* __restrict__ oh) {
  __shared__ __align__(16) _Float16 smem[32768];  // 64KB
  const int tid = threadIdx.x;
  const int lane = tid & 63, wave = tid >> 6;
  const int l31 = lane & 31, h = lane >> 5;
  const int b = blockIdx.z, hd = blockIdx.y;
  const int q0 = blockIdx.x * 512;

  const _Float16* Qrow = qh + (((size_t)(b * 16 + hd) * 2048 + q0 + wave * 32 + l31) * 64);
  f16x8 qf[4];
  #pragma unroll
  for (int s = 0; s < 4; s++) qf[s] = *(const f16x8*)(Qrow + s * 16 + h * 8);

  const char* Kb = (const char*)(kh + (size_t)b * 2048 * 64);
  const char* Vb = (const char*)(vth + (size_t)b * 64 * 2048);

  // staging: waves 0-7 stage K (chunks 0-511), waves 8-15 stage V (chunks 0-511)
  const bool isK = tid < 512;
  const char* src;
  int dstbase;
  {
    int c = isK ? tid : (tid - 512);
    int m = c >> 3, c8 = c & 7;
    int gc = c8 ^ (m & 7);
    if (isK) {
      int tsrc = (m & 51) | ((m & 4) << 1) | ((m & 8) >> 1);  // swap bits 2,3
      src = Kb + (size_t)tsrc * 128 + gc * 16;
      dstbase = c * 16;             // K region base 0
    } else {
      src = Vb + (size_t)m * 4096 + gc * 16;
      dstbase = 16384 + c * 16;     // V region base 16KB
    }
  }
  char* const ldsb = (char*)smem;  // K: +buf*8192 ; V: +16384+buf*8192
  const size_t srcstep = isK ? 8192 : 128;  // per-tile source advance (bytes)

  const int swz = l31 & 7;
  int ro[4][2];
  #pragma unroll
  for (int s = 0; s < 4; s++) {
    int ch = ((2 * s + h) ^ swz) << 4;
    ro[s][0] = l31 * 128 + ch;
    ro[s][1] = (l31 + 32) * 128 + ch;
  }

  float negm = 0.f, l_run = 0.f;   // negm = -m_run
  f32x16 oa0 = {}, oa1 = {};
  const f16x2 one2 = {(_Float16)1.0f, (_Float16)1.0f};

  auto STAGE = [&](int t, int buf) {
    gll16(src + (size_t)t * srcstep, ldsb + buf * 8192 + dstbase);
  };

  // prologue: tile 0 into buffer 0
  STAGE(0, 0);
  __syncthreads();

  for (int it = 0; it < 32; ++it) {
    const int cur = it & 1;
    const char* kb = ldsb + cur * 8192;
    const char* vb = kb + 16384;

    // prefetch next tile into other buffer (in flight during compute)
    if (it + 1 < 32) STAGE(it + 1, cur ^ 1);

    // ---- S^T = K . Q^T ; C-init = -m_run (free max-subtraction) ----
    f32x16 s0, s1;
    #pragma unroll
    for (int i = 0; i < 16; i++) { s0[i] = negm; s1[i] = negm; }
    #pragma unroll
    for (int s = 0; s < 4; s++) {
      f16x8 a0 = *(const f16x8*)(kb + ro[s][0]);
      f16x8 a1 = *(const f16x8*)(kb + ro[s][1]);
      s0 = MFMA32(a0, qf[s], s0);
      s1 = MFMA32(a1, qf[s], s1);
    }

    // ---- shifted row max (lane owns q-row l31; partner lane^32) ----
    float vm[8];
    #pragma unroll
    for (int i = 0; i < 8; i++)
      vm[i] = fmaxf(fmaxf(s0[i], s0[i + 8]), fmaxf(s1[i], s1[i + 8]));
    float pm = fmaxf(fmaxf(fmaxf(vm[0], vm[1]), fmaxf(vm[2], vm[3])),
                     fmaxf(fmaxf(vm[4], vm[5]), fmaxf(vm[6], vm[7])));
    pm = fmaxf(pm, __shfl_xor(pm, 32));

    if (__any(pm > 8.0f)) {  // defer-max trigger (rare, wave-uniform)
      float delta = fmaxf(pm, 0.f);
      float al = __builtin_amdgcn_exp2f(-delta);
      l_run *= al;
      oa0 *= al;
      oa1 *= al;
      negm -= delta;
      #pragma unroll
      for (int i = 0; i < 16; i++) { s0[i] -= delta; s1[i] -= delta; }
    }

    // ---- P = exp2(S) (already max-shifted; raw v_exp_f32, input <= +8) ----
    #pragma unroll
    for (int i = 0; i < 16; i++) {
      s0[i] = __builtin_amdgcn_exp2f(s0[i]);
      s1[i] = __builtin_amdgcn_exp2f(s1[i]);
    }

    // ---- pack to f16 (RTZ) + fdot2 row sums ----
    f16x2 pp[16];
    #pragma unroll
    for (int j = 0; j < 8; j++) pp[j] = PKRTZ(s0[2 * j], s0[2 * j + 1]);
    #pragma unroll
    for (int j = 0; j < 8; j++) pp[8 + j] = PKRTZ(s1[2 * j], s1[2 * j + 1]);

    float ps0 = 0.f, ps1 = 0.f, ps2 = 0.f, ps3 = 0.f;
    #pragma unroll
    for (int j = 0; j < 4; j++) {
      ps0 = __builtin_amdgcn_fdot2(pp[j], one2, ps0, false);
      ps1 = __builtin_amdgcn_fdot2(pp[4 + j], one2, ps1, false);
      ps2 = __builtin_amdgcn_fdot2(pp[8 + j], one2, ps2, false);
      ps3 = __builtin_amdgcn_fdot2(pp[12 + j], one2, ps3, false);
    }
    l_run += (ps0 + ps1) + (ps2 + ps3);

    // ---- P B-frags: pf[s] = pp[4s..4s+3] ----
    f16x8 pf[4];
    #pragma unroll
    for (int s = 0; s < 4; s++) {
      f16x4 lo = __builtin_shufflevector(pp[s * 4], pp[s * 4 + 1], 0, 1, 2, 3);
      f16x4 hi = __builtin_shufflevector(pp[s * 4 + 2], pp[s * 4 + 3], 0, 1, 2, 3);
      pf[s] = __builtin_shufflevector(lo, hi, 0, 1, 2, 3, 4, 5, 6, 7);
    }

    // ---- O^T += V^T . P^T ----
    #pragma unroll
    for (int s = 0; s < 4; s++) {
      f16x8 v0 = *(const f16x8*)(vb + ro[s][0]);
      f16x8 v1 = *(const f16x8*)(vb + ro[s][1]);
      oa0 = MFMA32(v0, pf[s], oa0);
      oa1 = MFMA32(v1, pf[s], oa1);
    }

    __syncthreads();  // drains vmcnt -> next tile staged; buffer safe to flip
  }

  // ---- epilogue: combine l halves, de-transpose O^T via swizzled LDS ----
  l_run += __shfl_xor(l_run, 32);
  _Float16* ob = smem + wave * 2048;  // [32 q][64 e] per wave; 16 x 4KB = 64KB
  float invl = 1.0f / l_run;
  #pragma unroll
  for (int rh = 0; rh < 4; rh++) {
    f16x4 t0, t1;
    #pragma unroll
    for (int j = 0; j < 4; j++) {
      t0[j] = (_Float16)(oa0[rh * 4 + j] * invl);
      t1[j] = (_Float16)(oa1[rh * 4 + j] * invl);
    }
    *(f16x4*)&ob[l31 * 64 + ((rh ^ swz) * 8) + h * 4] = t0;
    *(f16x4*)&ob[l31 * 64 + (((rh + 4) ^ swz) * 8) + h * 4] = t1;
  }
  const int q_ = lane >> 1, hf = lane & 1;
  const size_t orow = ((size_t)b * 2048 + q0 + wave * 32 + q_) * 1024 + hd * 64 + hf * 32;
  #pragma unroll
  for (int c = 0; c < 4; c++) {
    f16x8 v = *(const f16x8*)&ob[q_ * 64 + (((hf * 4 + c) ^ (q_ & 7)) * 8)];
    *(f16x8*)(oh + orow + c * 8) = v;
  }
}

extern "C" void kernel_launch(void* const* d_in, const int* in_sizes, int n_in,
                              void* d_out, int out_size, void* d_ws, size_t ws_size,
                              hipStream_t stream) {
  const float* x  = (const float*)d_in[0];
  const float* Wq = (const float*)d_in[1];
  const float* bq = (const float*)d_in[2];
  const float* Wk = (const float*)d_in[3];
  const float* bk = (const float*)d_in[4];
  const float* Wv = (const float*)d_in[5];
  const float* bv = (const float*)d_in[6];
  const float* Wo = (const float*)d_in[7];
  const float* bo = (const float*)d_in[8];
  float* out = (float*)d_out;
  char* ws = (char*)d_ws;

  _Float16* xh   = (_Float16*)(ws);
  _Float16* wqkv = (_Float16*)(ws + 16777216);
  _Float16* woT  = (_Float16*)(ws + 19136512);
  _Float16* qh   = (_Float16*)(ws + 21233664);
  _Float16* kh   = (_Float16*)(ws + 38010880);
  _Float16* vth  = (_Float16*)(ws + 39059456);
  _Float16* oh   = (_Float16*)(ws + 40108032);

  pack_all_kernel<<<12800, 256, 0, stream>>>(x, Wq, Wk, Wv, Wo, xh, wqkv, woT);
  gemm_qkv_kernel<<<dim3(64, 9), 256, 0, stream>>>(xh, wqkv, bq, bk, bv, qh, kh, vth);
  attn_kernel<<<dim3(4, 16, 4), 1024, 0, stream>>>(qh, kh, vth, oh);
  gemm_out_kernel<<<dim3(64, 8), 256, 0, stream>>>(oh, woT, bo, out);
}